// Round 2
// baseline (31826.849 us; speedup 1.0000x reference)
//
#include <hip/hip_runtime.h>
#include <cstddef>
#include <cstdint>

#define BB   64
#define TT   512
#define DD   300
#define HH   1024
#define NTH  256
#define NBLK 512
#define HB   2            // h-indices owned per block (NBLK*HB == HH)
#define D4   75           // DD/4
#define K4   256          // HH/4
#define KTOT 331          // K4 + D4
#define BN_EPS 1e-5f

__device__ __forceinline__ float4 fma4(float4 a, float4 b, float4 c) {
  c.x = fmaf(a.x, b.x, c.x);
  c.y = fmaf(a.y, b.y, c.y);
  c.z = fmaf(a.z, b.z, c.z);
  c.w = fmaf(a.w, b.w, c.w);
  return c;
}

__device__ __forceinline__ float sigmoid_f(float v) {
  v = fminf(fmaxf(v, -30.f), 30.f);
  return 1.f / (1.f + __expf(-v));
}

__device__ __forceinline__ float tanh_f(float v) {
  float e = __expf(fminf(fmaxf(2.f * v, -30.f), 30.f));
  return (e - 1.f) / (e + 1.f);
}

// Monotonic-epoch grid barrier (no cooperative API). barp[0] = arrival counter,
// barp[32] = epoch flag (separate cache line). Co-residency by capacity:
// 512 blocks at 2 blocks/CU occupancy x 256 CUs. Bounded spin as safety valve.
__device__ __forceinline__ void gridbar(unsigned* barp, unsigned ep) {
  __syncthreads();
  if (threadIdx.x == 0) {
    __threadfence();  // release: h writes visible device-wide
    unsigned old = __hip_atomic_fetch_add(&barp[0], 1u, __ATOMIC_ACQ_REL,
                                          __HIP_MEMORY_SCOPE_AGENT);
    if (old == ep * (unsigned)NBLK - 1u) {
      __hip_atomic_store(&barp[32], ep, __ATOMIC_RELEASE, __HIP_MEMORY_SCOPE_AGENT);
    } else {
      long spins = 0;
      while (__hip_atomic_load(&barp[32], __ATOMIC_ACQUIRE,
                               __HIP_MEMORY_SCOPE_AGENT) < ep) {
        __builtin_amdgcn_s_sleep(2);
        if (++spins > (1L << 23)) break;  // ~0.5s valve: fail visibly, never hang
      }
    }
    __threadfence();  // acquire side before reading fresh h
  }
  __syncthreads();
}

// x transpose: x[b][t][d] -> xT[t][d4][b] (float4 over d)
__global__ void xpose_k(const float* __restrict__ x, float4* __restrict__ xT) {
  int idx = blockIdx.x * blockDim.x + threadIdx.x;
  if (idx >= TT * D4 * BB) return;
  int b  = idx & 63;
  int j  = (idx >> 6) % D4;
  int t  = (idx >> 6) / D4;
  xT[idx] = *(const float4*)(x + (size_t)b * (TT * DD) + (size_t)t * DD + 4 * j);
}

__global__ void init_k(float* __restrict__ hbuf, unsigned* __restrict__ barp) {
  int idx = blockIdx.x * blockDim.x + threadIdx.x;
  const int n = 2 * K4 * BB * 4;  // both h ping-pong buffers, floats
  for (int i = idx; i < n; i += gridDim.x * blockDim.x) hbuf[i] = 0.f;
  if (idx < 64) barp[idx] = 0u;
}

__global__ void __launch_bounds__(NTH, 2)
lstm_main(const float* __restrict__ xsrc, const float* __restrict__ Wih,
          const float* __restrict__ Whh, const float* __restrict__ bih,
          const float* __restrict__ bhh, const float* __restrict__ gammap,
          const float* __restrict__ betap, const float* __restrict__ maskp,
          const float* __restrict__ tlbl, const float* __restrict__ fcw,
          const float* __restrict__ fcb, float* __restrict__ hbuf,
          float* __restrict__ pooled, unsigned* __restrict__ barp,
          float* __restrict__ outp, int xtflag) {
  // W staged ONCE into LDS for all 512 steps: 8 rows (4 gates x HB hidx),
  // [0,K4) = W_hh in float4-k, [K4,KTOT) = W_ih in float4-d.
  __shared__ float4 Ws[4 * HB][KTOT];           // 42.4 KB
  __shared__ float gate_s[4][HB][BB];           // 2 KB
  __shared__ float red_s[4][BB];                // 1 KB

  const int tid  = threadIdx.x;
  const int w    = tid >> 6;          // wave id 0..3
  const int lane = tid & 63;
  const int blk  = blockIdx.x;
  const int hb0  = blk * HB;

  // ---- stage W (once) ----
  for (int idx = tid; idx < 4 * HB * KTOT; idx += NTH) {
    int c = idx / KTOT, j = idx % KTOT;
    int row = (c >> 1) * HH + hb0 + (c & 1);
    float4 v;
    if (j < K4) v = *(const float4*)(Whh + (size_t)row * HH + 4 * j);
    else        v = *(const float4*)(Wih + (size_t)row * DD + 4 * (j - K4));
    Ws[c][j] = v;
  }

  // ---- dot-phase role: lane -> (batch b, column-pair cl) ----
  const int db = (w << 4) + (lane >> 2);  // batch row 0..63
  const int cl = lane & 3;                // columns cl and cl+4
  const int c0 = cl, c1 = cl + 4;
  const int row0 = (cl >> 1) * HH + hb0 + (cl & 1);
  const int row1 = ((cl >> 1) + 2) * HH + hb0 + (cl & 1);
  const float bias0 = bih[row0] + bhh[row0];
  const float bias1 = bih[row1] + bhh[row1];

  // ---- pointwise role: (p_hx, p_b), persistent c-state & pooled-max in regs ----
  const int p_hx = tid >> 6;
  const int p_b  = lane;
  float p_gamma = 0.f, p_beta = 0.f, p_mask = 0.f;
  if (p_hx < HB) {
    int hidx = hb0 + p_hx;
    p_gamma = gammap[hidx];
    p_beta  = betap[hidx];
    p_mask  = maskp[(size_t)p_b * HH + hidx];
  }
  float c_reg = 0.f;
  float pool_reg = -3.4e38f;
  __syncthreads();

  for (int s = 0; s < TT; ++s) {
    const float4* hcur = (const float4*)hbuf + (size_t)(s & 1) * (K4 * BB);
    float4 a0 = make_float4(0.f, 0.f, 0.f, 0.f);
    float4 a1 = make_float4(0.f, 0.f, 0.f, 0.f);

    if (xtflag) {  // x pre-transposed: [s][j][b] float4 — coalesced
      const float4* xp = (const float4*)xsrc + (size_t)s * (D4 * BB) + db;
      #pragma unroll 5
      for (int j = 0; j < D4; ++j) {
        float4 xv = xp[j * BB];
        a0 = fma4(xv, Ws[c0][K4 + j], a0);
        a1 = fma4(xv, Ws[c1][K4 + j], a1);
      }
    } else {       // fallback: strided reads straight from x
      const float* xb = xsrc + (size_t)db * (TT * DD) + (size_t)s * DD;
      #pragma unroll 5
      for (int j = 0; j < D4; ++j) {
        float4 xv = *(const float4*)(xb + 4 * j);
        a0 = fma4(xv, Ws[c0][K4 + j], a0);
        a1 = fma4(xv, Ws[c1][K4 + j], a1);
      }
    }
    #pragma unroll 8
    for (int j = 0; j < K4; ++j) {
      float4 hv = hcur[j * BB + db];
      a0 = fma4(hv, Ws[c0][j], a0);
      a1 = fma4(hv, Ws[c1][j], a1);
    }
    gate_s[(cl >> 1)][cl & 1][db]     = a0.x + a0.y + a0.z + a0.w + bias0;
    gate_s[(cl >> 1) + 2][cl & 1][db] = a1.x + a1.y + a1.z + a1.w + bias1;
    __syncthreads();

    if (p_hx < HB) {
      float gi = gate_s[0][p_hx][p_b];
      float gf = gate_s[1][p_hx][p_b];
      float gg = gate_s[2][p_hx][p_b];
      float go = gate_s[3][p_hx][p_b];
      float c2 = sigmoid_f(gf) * c_reg + sigmoid_f(gi) * tanh_f(gg);
      float h2 = sigmoid_f(go) * tanh_f(c2);
      c_reg = c2;
      // BatchNorm over batch: 64-lane butterfly (lane == batch)
      float s1 = h2, s2 = h2 * h2;
      #pragma unroll
      for (int off = 32; off; off >>= 1) {
        s1 += __shfl_xor(s1, off, 64);
        s2 += __shfl_xor(s2, off, 64);
      }
      float mu  = s1 * (1.f / 64.f);
      float var = fmaf(-mu, mu, s2 * (1.f / 64.f));
      float hn  = p_gamma * (h2 - mu) * rsqrtf(var + BN_EPS) + p_beta;
      pool_reg  = fmaxf(pool_reg, hn * p_mask);
      int hidx = hb0 + p_hx;
      float* hnxt = hbuf + (size_t)((s + 1) & 1) * (K4 * BB * 4);
      hnxt[(hidx >> 2) * (BB * 4) + p_b * 4 + (hidx & 3)] = h2;  // ping-pong
    }
    gridbar(barp, (unsigned)(s + 1));
  }

  if (p_hx < HB) {
    int hidx = hb0 + p_hx;
    pooled[(size_t)hidx * BB + p_b] = pool_reg;
  }
  gridbar(barp, (unsigned)(TT + 1));

  if (blk == 0) {
    float part = 0.f;
    for (int hh = w * 256; hh < w * 256 + 256; ++hh)
      part += pooled[(size_t)hh * BB + lane] * fcw[hh];
    red_s[w][lane] = part;
    __syncthreads();
    if (tid < BB) {
      float z = red_s[0][tid] + red_s[1][tid] + red_s[2][tid] + red_s[3][tid] + fcb[0];
      outp[1 + tid] = z;
      float sp = fmaxf(z, 0.f) + log1pf(__expf(-fabsf(z)));
      float lt = sp - z * tlbl[tid];
      #pragma unroll
      for (int off = 32; off; off >>= 1) lt += __shfl_xor(lt, off, 64);
      if (tid == 0) outp[0] = lt * (1.f / 64.f);
    }
  }
}

extern "C" void kernel_launch(void* const* d_in, const int* in_sizes, int n_in,
                              void* d_out, int out_size, void* d_ws, size_t ws_size,
                              hipStream_t stream) {
  const float* x     = (const float*)d_in[0];
  const float* tlbl  = (const float*)d_in[1];
  const float* maskp = (const float*)d_in[2];
  const float* Wih   = (const float*)d_in[3];
  const float* Whh   = (const float*)d_in[4];
  const float* bih   = (const float*)d_in[5];
  const float* bhh   = (const float*)d_in[6];
  const float* gammap= (const float*)d_in[7];
  const float* betap = (const float*)d_in[8];
  const float* fcw   = (const float*)d_in[9];
  const float* fcb   = (const float*)d_in[10];
  float* outp = (float*)d_out;

  const size_t xt_bytes   = (size_t)TT * D4 * BB * sizeof(float4);  // 39.3 MB
  const size_t h_bytes    = (size_t)2 * K4 * BB * sizeof(float4);   // 512 KB
  const size_t pool_bytes = (size_t)HH * BB * sizeof(float);        // 256 KB
  const size_t bar_bytes  = 256;
  const int use_xt = (ws_size >= xt_bytes + h_bytes + pool_bytes + bar_bytes) ? 1 : 0;

  char* p = (char*)d_ws;
  float4* xT = (float4*)p;
  if (use_xt) p += xt_bytes;
  float* hbuf = (float*)p;       p += h_bytes;
  float* pooled = (float*)p;     p += pool_bytes;
  unsigned* barp = (unsigned*)p;

  hipLaunchKernelGGL(init_k, dim3(128), dim3(NTH), 0, stream, hbuf, barp);
  if (use_xt) {
    int nthr = TT * D4 * BB;
    hipLaunchKernelGGL(xpose_k, dim3((nthr + NTH - 1) / NTH), dim3(NTH), 0, stream,
                       x, xT);
  }

  const float* xsrc = use_xt ? (const float*)xT : x;
  // Normal launch (NOT cooperative): co-residency by capacity arithmetic —
  // 45.4 KB LDS + launch_bounds(256,2) => 2 blocks/CU x 256 CUs = 512 slots.
  hipLaunchKernelGGL(lstm_main, dim3(NBLK), dim3(NTH), 0, stream,
                     xsrc, Wih, Whh, bih, bhh, gammap, betap, maskp, tlbl,
                     fcw, fcb, hbuf, pooled, barp, outp, use_xt);
}

// Round 3
// 29823.889 us; speedup vs baseline: 1.0672x; 1.0672x over previous
//
#include <hip/hip_runtime.h>
#include <cstddef>
#include <cstdint>

#define BB 64
#define TT 512
#define DD 300
#define HH 1024
#define NTH 256
#define NBLK 512
#define HB 2            // h-indices per block (NBLK*HB == HH)
#define D4 75           // DD/4
#define K4 256          // HH/4 (float4 groups of h)
#define CHUNK 16        // j4 groups per staged chunk
#define NCHUNK 16       // K4/CHUNK
#define BN_EPS 1e-5f
#define HBHALF (HH * BB * 2)  // bytes per bf16 h ping-pong image (128 KB)

typedef float f32x4 __attribute__((ext_vector_type(4)));
typedef unsigned u32x2 __attribute__((ext_vector_type(2)));

__device__ __forceinline__ f32x4 fma4(f32x4 a, f32x4 b, f32x4 c) {
  c.x = fmaf(a.x, b.x, c.x);
  c.y = fmaf(a.y, b.y, c.y);
  c.z = fmaf(a.z, b.z, c.z);
  c.w = fmaf(a.w, b.w, c.w);
  return c;
}
__device__ __forceinline__ float sigmoid_f(float v) {
  v = fminf(fmaxf(v, -30.f), 30.f);
  return 1.f / (1.f + __expf(-v));
}
__device__ __forceinline__ float tanh_f(float v) {
  float e = __expf(fminf(fmaxf(2.f * v, -30.f), 30.f));
  return (e - 1.f) / (e + 1.f);
}

// ---- LLC-coherent ops (sc0 sc1): complete at the coherence point shared by
// all XCDs. Cross-XCD visibility WITHOUT buffer_wbl2/buffer_inv fences.
__device__ __forceinline__ void ld2_sc(const void* a0, const void* a1,
                                       f32x4& r0, f32x4& r1) {
  // async: caller must s_waitcnt before using r0/r1
  asm volatile("global_load_dwordx4 %0, %2, off sc0 sc1\n\t"
               "global_load_dwordx4 %1, %3, off sc0 sc1"
               : "=&v"(r0), "=&v"(r1)
               : "v"(a0), "v"(a1)
               : "memory");
}
__device__ __forceinline__ unsigned ld_sc(const void* p) {
  unsigned v;
  asm volatile("global_load_dword %0, %1, off sc0 sc1\n\t"
               "s_waitcnt vmcnt(0)"
               : "=v"(v) : "v"(p) : "memory");
  return v;
}
__device__ __forceinline__ u32x2 ld2w_sc(const void* p) {
  u32x2 v;
  asm volatile("global_load_dwordx2 %0, %1, off sc0 sc1\n\t"
               "s_waitcnt vmcnt(0)"
               : "=v"(v) : "v"(p) : "memory");
  return v;
}
__device__ __forceinline__ void st_sc(void* p, unsigned v) {
  asm volatile("global_store_dword %0, %1, off sc0 sc1\n\t"
               "s_waitcnt vmcnt(0)"
               :: "v"(p), "v"(v) : "memory");
}
__device__ __forceinline__ void st_sc_short(void* p, unsigned v) {
  asm volatile("global_store_short %0, %1, off sc0 sc1\n\t"
               "s_waitcnt vmcnt(0)"
               :: "v"(p), "v"(v) : "memory");
}

// unpack 8 bf16 (two 4-packs, batches b and b+1) into two fp32 LDS cells
__device__ __forceinline__ void cvt2(f32x4 r, f32x4* cell) {
  unsigned d0 = __float_as_uint(r.x), d1 = __float_as_uint(r.y);
  unsigned d2 = __float_as_uint(r.z), d3 = __float_as_uint(r.w);
  f32x4 lo = {__uint_as_float(d0 << 16), __uint_as_float(d0 & 0xffff0000u),
              __uint_as_float(d1 << 16), __uint_as_float(d1 & 0xffff0000u)};
  f32x4 hi = {__uint_as_float(d2 << 16), __uint_as_float(d2 & 0xffff0000u),
              __uint_as_float(d3 << 16), __uint_as_float(d3 & 0xffff0000u)};
  cell[0] = lo;
  cell[1] = hi;
}

// Grid barrier: zero contended atomics. Arrive = per-block slot store (sc1),
// blk0 aggregates 512 slots in parallel (2 per thread), releases via flag.
__device__ __forceinline__ void grid_barrier(unsigned* slots, unsigned* flagp,
                                             int blk, int tid, unsigned ep) {
  __syncthreads();  // all prior sc1 stores in this block already vmcnt-drained
  if (tid == 0) st_sc(&slots[blk], ep);
  if (blk == 0) {
    bool done = false;
    int it = 0;
    do {
      u32x2 v = ld2w_sc(&slots[2 * tid]);
      int mine = (v.x >= ep) && (v.y >= ep);
      done = __syncthreads_and(mine) != 0;
      if (!done) __builtin_amdgcn_s_sleep(4);
    } while (!done && ++it < (1 << 20));  // valve: fail visibly, never hang
    if (tid == 0) st_sc(flagp, ep);
  } else {
    if (tid == 0) {
      long n = 0;
      while (ld_sc(flagp) < ep) {
        __builtin_amdgcn_s_sleep(4);
        if (++n > (1L << 22)) break;  // valve
      }
    }
    __syncthreads();
  }
}

__global__ void init_k(unsigned* __restrict__ zbase, int ndw) {
  int idx = blockIdx.x * blockDim.x + threadIdx.x;
  for (int i = idx; i < ndw; i += gridDim.x * blockDim.x) st_sc(zbase + i, 0u);
}

__global__ void __launch_bounds__(NTH, 2)
lstm_main(const float* __restrict__ x, const float* __restrict__ Wih,
          const float* __restrict__ Whh, const float* __restrict__ bih,
          const float* __restrict__ bhh, const float* __restrict__ gammap,
          const float* __restrict__ betap, const float* __restrict__ maskp,
          const float* __restrict__ tlbl, const float* __restrict__ fcw,
          const float* __restrict__ fcb, char* __restrict__ hb8,
          float* __restrict__ pooled, unsigned* __restrict__ slots,
          unsigned* __restrict__ flagp, float* __restrict__ outp) {
  __shared__ f32x4 Wsh[4 * HB][K4];      // 32 KB  W_hh rows (LDS-resident all steps)
  __shared__ f32x4 h_lds[2][CHUNK][BB];  // 32 KB  double-buffered h chunks (fp32)
  __shared__ float gate_s[4][HB][BB];    // 2 KB
  __shared__ float red_s[4][BB];         // 1 KB   (total 67.6 KB -> 2 blocks/CU)

  const int tid = threadIdx.x;
  const int w = tid >> 6;
  const int lane = tid & 63;
  const int blk = blockIdx.x;
  const int hb0 = blk * HB;

  // stage W_hh once
  for (int idx = tid; idx < 4 * HB * K4; idx += NTH) {
    int c = idx >> 8, j = idx & (K4 - 1);
    int row = (c >> 1) * HH + hb0 + (c & 1);
    Wsh[c][j] = *(const f32x4*)(Whh + (size_t)row * HH + 4 * j);
  }

  // dot-phase role: lane -> (batch db, column pair c0/c1)
  const int db = (w << 4) + (lane >> 2);
  const int cl = lane & 3;
  const int c0 = cl, c1 = cl + 4;
  const int row0 = (cl >> 1) * HH + hb0 + (cl & 1);
  const int row1 = ((cl >> 1) + 2) * HH + hb0 + (cl & 1);
  const float bias0 = bih[row0] + bhh[row0];
  const float bias1 = bih[row1] + bhh[row1];
  const f32x4* wi0 = (const f32x4*)(Wih + (size_t)row0 * DD);  // L2-resident
  const f32x4* wi1 = (const f32x4*)(Wih + (size_t)row1 * DD);
  const f32x4* xrow = (const f32x4*)(x + (size_t)db * (TT * DD));

  // pointwise role: wave = h-index, lane = batch
  const int p_hx = w;
  const int p_b = lane;
  float p_gamma = 0.f, p_beta = 0.f, p_mask = 0.f;
  if (p_hx < HB) {
    int hidx = hb0 + p_hx;
    p_gamma = gammap[hidx];
    p_beta = betap[hidx];
    p_mask = maskp[(size_t)p_b * HH + hidx];
  }
  float c_reg = 0.f;
  float pool_reg = -3.4e38f;

  const int jlA = tid >> 5;        // 0..7: chunk row this thread stages
  const int bb2 = (tid & 31) * 2;  // even batch pair
  __syncthreads();

  for (int s = 0; s < TT; ++s) {
    const char* hcur = hb8 + (size_t)(s & 1) * HBHALF;
    char* hnxt = hb8 + (size_t)((s + 1) & 1) * HBHALF;

    f32x4 a0 = {0.f, 0.f, 0.f, 0.f};
    f32x4 a1 = {0.f, 0.f, 0.f, 0.f};

    // x part: plain cached loads (inputs immutable; no invalidations anywhere)
    const f32x4* xr = xrow + s * D4;
#pragma unroll 5
    for (int j = 0; j < D4; ++j) {
      f32x4 xv = xr[j];
      a0 = fma4(xv, wi0[j], a0);
      a1 = fma4(xv, wi1[j], a1);
    }
    asm volatile("s_waitcnt vmcnt(0)" ::: "memory");  // drain compiler VM loads
    __builtin_amdgcn_sched_barrier(0);                // -> counted vmcnt valid

    // h part: 16 chunks, LDS double-buffer, 3-deep sc1 load pipeline
    f32x4 wv[3][2];
    const char* gbase = hcur + ((size_t)jlA * 64 + bb2) * 8;
    ld2_sc(gbase, gbase + 4096, wv[0][0], wv[0][1]);
    ld2_sc(gbase + 8192, gbase + 8192 + 4096, wv[1][0], wv[1][1]);
    ld2_sc(gbase + 16384, gbase + 16384 + 4096, wv[2][0], wv[2][1]);
    asm volatile("s_waitcnt vmcnt(4)" ::: "memory");  // chunk 0 landed
    __builtin_amdgcn_sched_barrier(0);
    cvt2(wv[0][0], &h_lds[0][jlA][bb2]);
    cvt2(wv[0][1], &h_lds[0][jlA + 8][bb2]);
    asm volatile("s_waitcnt lgkmcnt(0)" ::: "memory");
    __builtin_amdgcn_s_barrier();  // raw barrier: in-flight sc1 loads survive

#pragma unroll
    for (int c = 0; c < NCHUNK; ++c) {
      if (c + 3 < NCHUNK) {  // issue ahead (regs wv[c%3] were flushed last iter)
        const char* pa = gbase + (size_t)(c + 3) * 8192;
        ld2_sc(pa, pa + 4096, wv[(c + 3) % 3][0], wv[(c + 3) % 3][1]);
      }
#pragma unroll 8
      for (int jl = 0; jl < CHUNK; ++jl) {
        f32x4 hv = h_lds[c & 1][jl][db];
        a0 = fma4(hv, Wsh[c0][c * CHUNK + jl], a0);
        a1 = fma4(hv, Wsh[c1][c * CHUNK + jl], a1);
      }
      if (c + 1 < NCHUNK) {
        if (c <= NCHUNK - 4) {
          asm volatile("s_waitcnt vmcnt(4)" ::: "memory");  // c+1 done, c+2/c+3 fly
        } else if (c == NCHUNK - 3) {
          asm volatile("s_waitcnt vmcnt(2)" ::: "memory");
        } else {
          asm volatile("s_waitcnt vmcnt(0)" ::: "memory");
        }
        __builtin_amdgcn_sched_barrier(0);
        cvt2(wv[(c + 1) % 3][0], &h_lds[(c + 1) & 1][jlA][bb2]);
        cvt2(wv[(c + 1) % 3][1], &h_lds[(c + 1) & 1][jlA + 8][bb2]);
        asm volatile("s_waitcnt lgkmcnt(0)" ::: "memory");
        __builtin_amdgcn_s_barrier();
      }
    }

    gate_s[(cl >> 1)][cl & 1][db] = a0.x + a0.y + a0.z + a0.w + bias0;
    gate_s[(cl >> 1) + 2][cl & 1][db] = a1.x + a1.y + a1.z + a1.w + bias1;
    __syncthreads();  // VM empty here: full drain is free

    if (p_hx < HB) {
      float gi = gate_s[0][p_hx][p_b];
      float gf = gate_s[1][p_hx][p_b];
      float gg = gate_s[2][p_hx][p_b];
      float go = gate_s[3][p_hx][p_b];
      float c2 = sigmoid_f(gf) * c_reg + sigmoid_f(gi) * tanh_f(gg);
      float h2 = sigmoid_f(go) * tanh_f(c2);
      c_reg = c2;
      float s1 = h2, s2 = h2 * h2;  // BN over batch: 64-lane butterfly
#pragma unroll
      for (int off = 32; off; off >>= 1) {
        s1 += __shfl_xor(s1, off, 64);
        s2 += __shfl_xor(s2, off, 64);
      }
      float mu = s1 * (1.f / 64.f);
      float var = fmaf(-mu, mu, s2 * (1.f / 64.f));
      float hn = p_gamma * (h2 - mu) * rsqrtf(var + BN_EPS) + p_beta;
      pool_reg = fmaxf(pool_reg, hn * p_mask);
      int hidx = hb0 + p_hx;
      unsigned hu = __float_as_uint(h2);  // fp32 -> bf16 RNE
      unsigned b16 = (hu + 0x7fffu + ((hu >> 16) & 1u)) >> 16;
      size_t usidx = ((size_t)(hidx >> 2) * 64 + p_b) * 4 + (hidx & 3);
      st_sc_short(hnxt + usidx * 2, b16);  // includes vmcnt(0) drain
    }
    grid_barrier(slots, flagp, blk, tid, (unsigned)(s + 1));
  }

  if (p_hx < HB) {
    int hidx = hb0 + p_hx;
    st_sc((unsigned*)&pooled[(size_t)hidx * BB + p_b], __float_as_uint(pool_reg));
  }
  __syncthreads();
  if (tid == 0) st_sc(&slots[blk], (unsigned)(TT + 1));
  if (blk != 0) return;  // publish-only: non-zero blocks exit

  {
    bool done = false;
    int it = 0;
    do {
      u32x2 v = ld2w_sc(&slots[2 * tid]);
      int mine = (v.x >= (unsigned)(TT + 1)) && (v.y >= (unsigned)(TT + 1));
      done = __syncthreads_and(mine) != 0;
      if (!done) __builtin_amdgcn_s_sleep(4);
    } while (!done && ++it < (1 << 20));
  }
  // pooled lines were sc1-written (never L2-allocated): plain reads fetch LLC
  float part = 0.f;
  for (int hh = w * 256; hh < w * 256 + 256; ++hh)
    part += pooled[(size_t)hh * BB + lane] * fcw[hh];
  red_s[w][lane] = part;
  __syncthreads();
  if (tid < BB) {
    float z = red_s[0][tid] + red_s[1][tid] + red_s[2][tid] + red_s[3][tid] + fcb[0];
    outp[1 + tid] = z;
    float sp = fmaxf(z, 0.f) + log1pf(__expf(-fabsf(z)));
    float lt = sp - z * tlbl[tid];
#pragma unroll
    for (int off = 32; off; off >>= 1) lt += __shfl_xor(lt, off, 64);
    if (tid == 0) outp[0] = lt * (1.f / 64.f);
  }
}

extern "C" void kernel_launch(void* const* d_in, const int* in_sizes, int n_in,
                              void* d_out, int out_size, void* d_ws, size_t ws_size,
                              hipStream_t stream) {
  const float* x = (const float*)d_in[0];
  const float* tlbl = (const float*)d_in[1];
  const float* maskp = (const float*)d_in[2];
  const float* Wih = (const float*)d_in[3];
  const float* Whh = (const float*)d_in[4];
  const float* bih = (const float*)d_in[5];
  const float* bhh = (const float*)d_in[6];
  const float* gammap = (const float*)d_in[7];
  const float* betap = (const float*)d_in[8];
  const float* fcw = (const float*)d_in[9];
  const float* fcb = (const float*)d_in[10];
  float* outp = (float*)d_out;

  // ws layout: [slots 512 dw | pad | flag] (4 KB) | hb bf16 ping-pong (256 KB)
  //            | pooled (256 KB f32)
  unsigned* slots = (unsigned*)d_ws;
  unsigned* flagp = slots + 768;
  char* hb8 = (char*)d_ws + 4096;
  float* pooled = (float*)((char*)d_ws + 4096 + 2 * HBHALF);

  int ndw = (4096 + 2 * HBHALF) / 4;  // zero slots+flag+hb each call (replay-safe)
  hipLaunchKernelGGL(init_k, dim3(256), dim3(NTH), 0, stream, (unsigned*)d_ws, ndw);

  hipLaunchKernelGGL(lstm_main, dim3(NBLK), dim3(NTH), 0, stream,
                     x, Wih, Whh, bih, bhh, gammap, betap, maskp, tlbl,
                     fcw, fcb, hb8, pooled, slots, flagp, outp);
}

// Round 4
// 6135.691 us; speedup vs baseline: 5.1872x; 4.8607x over previous
//
#include <hip/hip_runtime.h>
#include <cstddef>
#include <cstdint>

#define BB 64
#define TT 512
#define DD 300
#define HH 1024
#define NTH 256
#define NBLK 128
#define HB 8                  // h-indices per block
#define XPAD 320              // x K padded to 10*32
#define KS_X 10
#define KS_H 32
#define KS_T 42
#define BN_EPS 1e-5f

typedef short short8 __attribute__((ext_vector_type(8)));
typedef float f32x4 __attribute__((ext_vector_type(4)));

__device__ __forceinline__ float sigmoid_f(float v) {
  v = fminf(fmaxf(v, -30.f), 30.f);
  return 1.f / (1.f + __expf(-v));
}
__device__ __forceinline__ float tanh_f(float v) {
  float e = __expf(fminf(fmaxf(2.f * v, -30.f), 30.f));
  return (e - 1.f) / (e + 1.f);
}
__device__ __forceinline__ unsigned short tobf(float f) {
  unsigned u = __float_as_uint(f);
  u += 0x7fffu + ((u >> 16) & 1u);
  return (unsigned short)(u >> 16);
}

// ---- LLC-coherent (sc0 sc1) and cached vmem ops; ALL in-loop vmem is inline
// asm so counted vmcnt bookkeeping stays exact (no compiler vmem in the loop).
__device__ __forceinline__ void ldA_sc(const void* p, short8& d) {
  asm volatile("global_load_dwordx4 %0, %1, off sc0 sc1"
               : "=v"(d) : "v"(p) : "memory");
}
__device__ __forceinline__ void ldA_nc(const void* p, short8& d) {
  asm volatile("global_load_dwordx4 %0, %1, off"
               : "=v"(d) : "v"(p) : "memory");
}
__device__ __forceinline__ void ld4_sc(const void* p, f32x4& d) {
  asm volatile("global_load_dwordx4 %0, %1, off sc0 sc1"
               : "=v"(d) : "v"(p) : "memory");
}
__device__ __forceinline__ unsigned ld_sc(const void* p) {
  unsigned v;
  asm volatile("global_load_dword %0, %1, off sc0 sc1\n\ts_waitcnt vmcnt(0)"
               : "=v"(v) : "v"(p) : "memory");
  return v;
}
__device__ __forceinline__ void st_sc32(void* p, unsigned v) {
  asm volatile("global_store_dword %0, %1, off sc0 sc1\n\ts_waitcnt vmcnt(0)"
               :: "v"(p), "v"(v) : "memory");
}
// counted wait + rule-18 fence (sched_barrier stops MFMA hoisting past the wait)
#define WAITV(N)                                                   \
  do {                                                             \
    asm volatile("s_waitcnt vmcnt(" #N ")" ::: "memory");          \
    __builtin_amdgcn_sched_barrier(0);                             \
  } while (0)

__device__ __forceinline__ f32x4 mfma16(short8 a, short8 b, f32x4 c) {
  return __builtin_amdgcn_mfma_f32_16x16x32_bf16(a, b, c, 0, 0, 0);
}

// poll all producer slots >= ep (one LLC round-trip per retry; no global barrier)
__device__ __forceinline__ void poll_ge(const unsigned* slots, int tid, unsigned ep) {
  int it = 0;
  for (;;) {
    int ok = 1;
    if (tid < NBLK) ok = (ld_sc(&slots[tid]) >= ep) ? 1 : 0;
    if (__syncthreads_and(ok)) break;
    if (++it > (1 << 20)) break;  // valve: fail visibly, never hang
    __builtin_amdgcn_s_sleep(1);
  }
}

__global__ void init_k(unsigned* __restrict__ base, int ndw) {
  int idx = blockIdx.x * blockDim.x + threadIdx.x;
  for (int i = idx; i < ndw; i += gridDim.x * blockDim.x) st_sc32(base + i, 0u);
}

// x [b][t][d] f32 -> xbf [t][b][XPAD] bf16 (zero-padded)
__global__ void xcvt_k(const float* __restrict__ x, unsigned short* __restrict__ xbf) {
  const int total = TT * BB * XPAD;
  for (int idx = blockIdx.x * blockDim.x + threadIdx.x; idx < total;
       idx += gridDim.x * blockDim.x) {
    int kx = idx % XPAD;
    int tb = idx / XPAD;
    int b = tb % BB, t = tb / BB;
    float v = (kx < DD) ? x[(size_t)b * (TT * DD) + (size_t)t * DD + kx] : 0.f;
    xbf[idx] = tobf(v);
  }
}

__global__ void __launch_bounds__(NTH, 1)
lstm_mfma(const float* __restrict__ Wih, const float* __restrict__ Whh,
          const float* __restrict__ bih, const float* __restrict__ bhh,
          const float* __restrict__ gammap, const float* __restrict__ betap,
          const float* __restrict__ maskp, const float* __restrict__ tlbl,
          const float* __restrict__ fcw, const float* __restrict__ fcb,
          const unsigned short* __restrict__ xbf, unsigned short* __restrict__ hbuf,
          float* __restrict__ partial, unsigned* __restrict__ slots,
          float* __restrict__ outp) {
  // B-operand in MFMA fragment layout: Wlds[nt][ks][lane] = 8 bf16 of
  // B[k = ks*32 + (lane>>4)*8 + e][col = nt*16 + (lane&15)]. Lane-linear 16B
  // => conflict-free ds_read_b128. ks 0..31 = W_hh, 32..41 = W_ih (padded).
  __shared__ short8 Wlds[2][KS_T][64];  // 84 KB
  __shared__ float Cs[64][33];          // 8.4 KB, +1 pad kills write conflicts
  __shared__ float red_s[4][64];        // 1 KB

  const int tid = threadIdx.x;
  const int w = tid >> 6, l = tid & 63;
  const int blk = blockIdx.x;
  const int hb0 = blk * HB;

  // ---- stage W as bf16 fragments (once) ----
  for (int idx = tid; idx < 2 * KS_T * 64; idx += NTH) {
    int nt = idx / (KS_T * 64);
    int rem = idx % (KS_T * 64);
    int ks = rem >> 6, ll = rem & 63;
    int colq = nt * 16 + (ll & 15);          // block-local col 0..31
    int g = colq >> 3, j = colq & 7;         // gate, h-sub-index
    int r = g * HH + hb0 + j;                // global W row
    int k0 = (ll >> 4) * 8;
    float v[8];
    if (ks < KS_H) {
      const float* src = Whh + (size_t)r * HH + ks * 32 + k0;
      f32x4 u0 = *(const f32x4*)src;
      f32x4 u1 = *(const f32x4*)(src + 4);
      v[0] = u0.x; v[1] = u0.y; v[2] = u0.z; v[3] = u0.w;
      v[4] = u1.x; v[5] = u1.y; v[6] = u1.z; v[7] = u1.w;
    } else {
      int d0 = (ks - KS_H) * 32 + k0;
#pragma unroll
      for (int e = 0; e < 8; ++e)
        v[e] = (d0 + e < DD) ? Wih[(size_t)r * DD + d0 + e] : 0.f;  // guarded: no OOB
    }
    short8 pk;
#pragma unroll
    for (int e = 0; e < 8; ++e) pk[e] = (short)tobf(v[e]);
    Wlds[nt][ks][ll] = pk;
  }

  // ---- MFMA wave roles: wave w -> (M-pair mp = w>>1, N-tile nt = w&1) ----
  const int nt = w & 1, mp = w >> 1;
  const int lrow = l & 15, lk = (l >> 4) * 8;
  const int row0 = mp * 32 + lrow, row1 = row0 + 16;

  // ---- pointwise roles: lane = batch, wave w -> h-sub j0=2w, j1=2w+1 ----
  const int b = l, j0 = 2 * w, j1 = 2 * w + 1;
  const float gam0 = gammap[hb0 + j0], gam1 = gammap[hb0 + j1];
  const float bet0 = betap[hb0 + j0], bet1 = betap[hb0 + j1];
  const float msk0 = maskp[(size_t)b * HH + hb0 + j0];
  const float msk1 = maskp[(size_t)b * HH + hb0 + j1];
  const float biI0 = bih[0 * HH + hb0 + j0] + bhh[0 * HH + hb0 + j0];
  const float biF0 = bih[1 * HH + hb0 + j0] + bhh[1 * HH + hb0 + j0];
  const float biG0 = bih[2 * HH + hb0 + j0] + bhh[2 * HH + hb0 + j0];
  const float biO0 = bih[3 * HH + hb0 + j0] + bhh[3 * HH + hb0 + j0];
  const float biI1 = bih[0 * HH + hb0 + j1] + bhh[0 * HH + hb0 + j1];
  const float biF1 = bih[1 * HH + hb0 + j1] + bhh[1 * HH + hb0 + j1];
  const float biG1 = bih[2 * HH + hb0 + j1] + bhh[2 * HH + hb0 + j1];
  const float biO1 = bih[3 * HH + hb0 + j1] + bhh[3 * HH + hb0 + j1];
  const float fw0 = fcw[hb0 + j0], fw1 = fcw[hb0 + j1];
  float creg0 = 0.f, creg1 = 0.f;
  float pool0 = -3.4e38f, pool1 = -3.4e38f;
  __syncthreads();

  for (int s = 0; s < TT; ++s) {
    const unsigned short* hc = hbuf + (size_t)(s & 1) * (BB * HH);
    unsigned short* hnx = hbuf + (size_t)((s + 1) & 1) * (BB * HH);

    // issue x A-frag loads (plain cached; x immutable -> L2-served)
    const unsigned short* px0 = xbf + ((size_t)s * BB + row0) * XPAD + lk;
    const unsigned short* px1 = px0 + 16 * XPAD;
    short8 xa0[KS_X], xa1[KS_X];
#pragma unroll
    for (int i = 0; i < KS_X; ++i) {
      ldA_nc(px0 + i * 32, xa0[i]);
      ldA_nc(px1 + i * 32, xa1[i]);
    }
    // wait for h_s publication (overlaps x-load latency; poll drains vmcnt
    // in waves 0/1 which is harmless)
    poll_ge(slots, tid, (unsigned)s);

    const unsigned short* ph0 = hc + (size_t)row0 * HH + lk;
    const unsigned short* ph1 = hc + (size_t)row1 * HH + lk;
    short8 ha0[KS_H], ha1[KS_H];
    // chunk 0 (k-steps 0..7): 16 sc loads
#pragma unroll
    for (int i = 0; i < 8; ++i) {
      ldA_sc(ph0 + i * 32, ha0[i]);
      ldA_sc(ph1 + i * 32, ha1[i]);
    }
    WAITV(16);  // x loads retired (in-order); chunk0 may still fly
    f32x4 acc0 = {0.f, 0.f, 0.f, 0.f}, acc1 = {0.f, 0.f, 0.f, 0.f};
#pragma unroll
    for (int i = 0; i < KS_X; ++i) {
      short8 bf = Wlds[nt][KS_H + i][l];
      acc0 = mfma16(xa0[i], bf, acc0);
      acc1 = mfma16(xa1[i], bf, acc1);
    }
    // chunks 1,2 (k-steps 8..23): 32 loads, outstanding <= 48 (< vmcnt cap 63)
#pragma unroll
    for (int i = 8; i < 24; ++i) {
      ldA_sc(ph0 + i * 32, ha0[i]);
      ldA_sc(ph1 + i * 32, ha1[i]);
    }
    WAITV(32);  // chunk 0 complete
#pragma unroll
    for (int i = 0; i < 8; ++i) {
      short8 bf = Wlds[nt][i][l];
      acc0 = mfma16(ha0[i], bf, acc0);
      acc1 = mfma16(ha1[i], bf, acc1);
    }
#pragma unroll
    for (int i = 24; i < 32; ++i) {  // chunk 3
      ldA_sc(ph0 + i * 32, ha0[i]);
      ldA_sc(ph1 + i * 32, ha1[i]);
    }
    WAITV(32);  // chunk 1 complete
#pragma unroll
    for (int i = 8; i < 16; ++i) {
      short8 bf = Wlds[nt][i][l];
      acc0 = mfma16(ha0[i], bf, acc0);
      acc1 = mfma16(ha1[i], bf, acc1);
    }
    WAITV(16);  // chunk 2 complete
#pragma unroll
    for (int i = 16; i < 24; ++i) {
      short8 bf = Wlds[nt][i][l];
      acc0 = mfma16(ha0[i], bf, acc0);
      acc1 = mfma16(ha1[i], bf, acc1);
    }
    WAITV(0);   // chunk 3 complete
#pragma unroll
    for (int i = 24; i < 32; ++i) {
      short8 bf = Wlds[nt][i][l];
      acc0 = mfma16(ha0[i], bf, acc0);
      acc1 = mfma16(ha1[i], bf, acc1);
    }

    // ---- exchange C through LDS (C layout: col=lane&15, row=(lane>>4)*4+r) ----
    {
      int crow = mp * 32 + (l >> 4) * 4;
      int ccol = nt * 16 + (l & 15);
#pragma unroll
      for (int r = 0; r < 4; ++r) {
        Cs[crow + r][ccol] = acc0[r];
        Cs[crow + 16 + r][ccol] = acc1[r];
      }
    }
    __syncthreads();

    // ---- pointwise + BN + pool + publish ----
    float gI0 = Cs[b][j0] + biI0, gF0 = Cs[b][8 + j0] + biF0;
    float gG0 = Cs[b][16 + j0] + biG0, gO0 = Cs[b][24 + j0] + biO0;
    float gI1 = Cs[b][j1] + biI1, gF1 = Cs[b][8 + j1] + biF1;
    float gG1 = Cs[b][16 + j1] + biG1, gO1 = Cs[b][24 + j1] + biO1;
    float c20 = sigmoid_f(gF0) * creg0 + sigmoid_f(gI0) * tanh_f(gG0);
    float h20 = sigmoid_f(gO0) * tanh_f(c20);
    float c21 = sigmoid_f(gF1) * creg1 + sigmoid_f(gI1) * tanh_f(gG1);
    float h21 = sigmoid_f(gO1) * tanh_f(c21);
    creg0 = c20;
    creg1 = c21;
    float s10 = h20, s20 = h20 * h20, s11 = h21, s21 = h21 * h21;
#pragma unroll
    for (int off = 32; off; off >>= 1) {
      s10 += __shfl_xor(s10, off, 64);
      s20 += __shfl_xor(s20, off, 64);
      s11 += __shfl_xor(s11, off, 64);
      s21 += __shfl_xor(s21, off, 64);
    }
    float mu0 = s10 * (1.f / 64.f), var0 = fmaf(-mu0, mu0, s20 * (1.f / 64.f));
    float mu1 = s11 * (1.f / 64.f), var1 = fmaf(-mu1, mu1, s21 * (1.f / 64.f));
    float hn0 = gam0 * (h20 - mu0) * rsqrtf(var0 + BN_EPS) + bet0;
    float hn1 = gam1 * (h21 - mu1) * rsqrtf(var1 + BN_EPS) + bet1;
    pool0 = fmaxf(pool0, hn0 * msk0);
    pool1 = fmaxf(pool1, hn1 * msk1);
    unsigned pk = (unsigned)tobf(h20) | ((unsigned)tobf(h21) << 16);
    st_sc32(hnx + (size_t)b * HH + hb0 + j0, pk);  // raw h2 carried fwd; drains
    __syncthreads();
    if (tid == 0) st_sc32(&slots[blk], (unsigned)(s + 1));  // publish h_{s+1}
  }

  // ---- per-block FC partial ----
  red_s[w][b] = pool0 * fw0 + pool1 * fw1;
  __syncthreads();
  if (tid < BB) {
    float part = red_s[0][tid] + red_s[1][tid] + red_s[2][tid] + red_s[3][tid];
    st_sc32(&partial[(size_t)tid * NBLK + blk], __float_as_uint(part));
  }
  __syncthreads();
  if (tid == 0) st_sc32(&slots[blk], (unsigned)(TT + 1));
  if (blk != 0) return;

  // ---- block 0: final reduction + loss ----
  poll_ge(slots, tid, (unsigned)(TT + 1));
  {
    int fb = tid & 63, q = tid >> 6;
    const float* pp = partial + ((size_t)fb * NBLK + q * 32);
    f32x4 v0, v1, v2, v3, v4, v5, v6, v7;
    ld4_sc(pp + 0, v0);  ld4_sc(pp + 4, v1);  ld4_sc(pp + 8, v2);  ld4_sc(pp + 12, v3);
    ld4_sc(pp + 16, v4); ld4_sc(pp + 20, v5); ld4_sc(pp + 24, v6); ld4_sc(pp + 28, v7);
    WAITV(0);
    float sum = v0.x + v0.y + v0.z + v0.w + v1.x + v1.y + v1.z + v1.w +
                v2.x + v2.y + v2.z + v2.w + v3.x + v3.y + v3.z + v3.w +
                v4.x + v4.y + v4.z + v4.w + v5.x + v5.y + v5.z + v5.w +
                v6.x + v6.y + v6.z + v6.w + v7.x + v7.y + v7.z + v7.w;
    red_s[q][fb] = sum;
  }
  __syncthreads();
  if (tid < BB) {
    float z = red_s[0][tid] + red_s[1][tid] + red_s[2][tid] + red_s[3][tid] + fcb[0];
    outp[1 + tid] = z;
    float sp = fmaxf(z, 0.f) + log1pf(__expf(-fabsf(z)));
    float lt = sp - z * tlbl[tid];
#pragma unroll
    for (int off = 32; off; off >>= 1) lt += __shfl_xor(lt, off, 64);
    if (tid == 0) outp[0] = lt * (1.f / 64.f);
  }
}

extern "C" void kernel_launch(void* const* d_in, const int* in_sizes, int n_in,
                              void* d_out, int out_size, void* d_ws, size_t ws_size,
                              hipStream_t stream) {
  const float* x = (const float*)d_in[0];
  const float* tlbl = (const float*)d_in[1];
  const float* maskp = (const float*)d_in[2];
  const float* Wih = (const float*)d_in[3];
  const float* Whh = (const float*)d_in[4];
  const float* bih = (const float*)d_in[5];
  const float* bhh = (const float*)d_in[6];
  const float* gammap = (const float*)d_in[7];
  const float* betap = (const float*)d_in[8];
  const float* fcw = (const float*)d_in[9];
  const float* fcb = (const float*)d_in[10];
  float* outp = (float*)d_out;

  // ws: slots(512B)+pad @0 | hbuf 2x128KB @4KB | partial 32KB | xbf 20.5MB
  // total ~21.3 MB
  unsigned* slots = (unsigned*)d_ws;
  unsigned short* hbuf = (unsigned short*)((char*)d_ws + 4096);
  float* partial = (float*)((char*)d_ws + 4096 + 2 * BB * HH * 2);
  unsigned short* xbf =
      (unsigned short*)((char*)d_ws + 4096 + 2 * BB * HH * 2 + BB * NBLK * 4);

  // zero slots + h image 0 (contiguous from ws base: 4096 + 128KB)
  int ndw = (4096 + BB * HH * 2) / 4;
  hipLaunchKernelGGL(init_k, dim3(64), dim3(NTH), 0, stream, (unsigned*)d_ws, ndw);
  hipLaunchKernelGGL(xcvt_k, dim3(2048), dim3(NTH), 0, stream, x, xbf);
  hipLaunchKernelGGL(lstm_mfma, dim3(NBLK), dim3(NTH), 0, stream,
                     Wih, Whh, bih, bhh, gammap, betap, maskp, tlbl, fcw, fcb,
                     xbf, hbuf, partial, slots, outp);
}

// Round 5
// 2695.291 us; speedup vs baseline: 11.8083x; 2.2764x over previous
//
#include <hip/hip_runtime.h>
#include <cstddef>
#include <cstdint>

#define BB 64
#define TT 512
#define HH 1024
#define DD 300
#define NTH 256
#define NBLK 128
#define HB 8                  // h-indices per block
#define XPAD 320              // x K padded to 10*32
#define KS_X 10
#define KS_H 32
#define BN_EPS 1e-5f

typedef short short8 __attribute__((ext_vector_type(8)));
typedef float f32x4 __attribute__((ext_vector_type(4)));
typedef unsigned u32x2 __attribute__((ext_vector_type(2)));

__device__ __forceinline__ float sigmoid_f(float v) {
  v = fminf(fmaxf(v, -30.f), 30.f);
  return 1.f / (1.f + __expf(-v));
}
__device__ __forceinline__ float tanh_f(float v) {
  float e = __expf(fminf(fmaxf(2.f * v, -30.f), 30.f));
  return (e - 1.f) / (e + 1.f);
}
__device__ __forceinline__ unsigned short tobf(float f) {
  unsigned u = __float_as_uint(f);
  u += 0x7fffu + ((u >> 16) & 1u);
  return (unsigned short)(u >> 16);
}

// ---- LLC-coherent (sc0 sc1) + cached vmem ops; all in-loop vmem is inline asm
// so counted-vmcnt bookkeeping stays exact.
__device__ __forceinline__ void ldA_sc(const void* p, short8& d) {
  asm volatile("global_load_dwordx4 %0, %1, off sc0 sc1"
               : "=v"(d) : "v"(p) : "memory");
}
__device__ __forceinline__ void ldA_nc(const void* p, short8& d) {
  asm volatile("global_load_dwordx4 %0, %1, off"
               : "=v"(d) : "v"(p) : "memory");
}
__device__ __forceinline__ void ld4_sc(const void* p, f32x4& d) {
  asm volatile("global_load_dwordx4 %0, %1, off sc0 sc1"
               : "=v"(d) : "v"(p) : "memory");
}
__device__ __forceinline__ u32x2 ld2w_sc(const void* p) {
  u32x2 v;
  asm volatile("global_load_dwordx2 %0, %1, off sc0 sc1\n\ts_waitcnt vmcnt(0)"
               : "=v"(v) : "v"(p) : "memory");
  return v;
}
__device__ __forceinline__ void st_sc32(void* p, unsigned v) {
  asm volatile("global_store_dword %0, %1, off sc0 sc1\n\ts_waitcnt vmcnt(0)"
               :: "v"(p), "v"(v) : "memory");
}
#define WAITV(N)                                                   \
  do {                                                             \
    asm volatile("s_waitcnt vmcnt(" #N ")" ::: "memory");          \
    __builtin_amdgcn_sched_barrier(0);                             \
  } while (0)

__device__ __forceinline__ f32x4 mfma16(short8 a, short8 b, f32x4 c) {
  return __builtin_amdgcn_mfma_f32_16x16x32_bf16(a, b, c, 0, 0, 0);
}

// wave0-only poll: lane i checks slots[2i], slots[2i+1] (one dwordx2/lane)
__device__ __forceinline__ void poll_ge(const unsigned* slots, int tid, unsigned ep) {
  int it = 0;
  for (;;) {
    int ok = 1;
    if (tid < 64) {
      u32x2 v = ld2w_sc(&slots[2 * tid]);
      ok = (v.x >= ep && v.y >= ep) ? 1 : 0;
    }
    if (__syncthreads_and(ok)) break;
    if (++it > (1 << 20)) break;  // valve: fail visibly, never hang
    if (it > 1) __builtin_amdgcn_s_sleep(1);
  }
}

__global__ void init_k(unsigned* __restrict__ base, int ndw) {
  int idx = blockIdx.x * blockDim.x + threadIdx.x;
  for (int i = idx; i < ndw; i += gridDim.x * blockDim.x) st_sc32(base + i, 0u);
}

// x [b][t][d] f32 -> xbf [t][b][XPAD] bf16 (zero-padded)
__global__ void xcvt_k(const float* __restrict__ x, unsigned short* __restrict__ xbf) {
  const int total = TT * BB * XPAD;
  for (int idx = blockIdx.x * blockDim.x + threadIdx.x; idx < total;
       idx += gridDim.x * blockDim.x) {
    int kx = idx % XPAD;
    int tb = idx / XPAD;
    int b = tb % BB, t = tb / BB;
    float v = (kx < DD) ? x[(size_t)b * (TT * DD) + (size_t)t * DD + kx] : 0.f;
    xbf[idx] = tobf(v);
  }
}

__global__ void __launch_bounds__(NTH, 1)
lstm_mfma(const float* __restrict__ Wih, const float* __restrict__ Whh,
          const float* __restrict__ bih, const float* __restrict__ bhh,
          const float* __restrict__ gammap, const float* __restrict__ betap,
          const float* __restrict__ maskp, const float* __restrict__ tlbl,
          const float* __restrict__ fcw, const float* __restrict__ fcb,
          const unsigned short* __restrict__ xbf, unsigned short* __restrict__ hbuf,
          float* __restrict__ partial, unsigned* __restrict__ slots,
          float* __restrict__ outp) {
  // B-operand fragments: Wlds[nt][ks][lane] = 8 bf16 of
  // B[k = ks*32 + (lane>>4)*8 + e][col = nt*16 + (lane&15)].
  // ks 0..31 = W_hh, 32..41 = W_ih (zero-padded). Lane-linear ds_read_b128.
  __shared__ short8 Wlds[2][KS_H + KS_X][64];  // 84 KB
  __shared__ float Cs[64][33];                 // 8.4 KB (+1 pad)
  __shared__ float red_s[4][64];               // 1 KB

  const int tid = threadIdx.x;
  const int w = tid >> 6, l = tid & 63;
  const int blk = blockIdx.x;
  const int hb0 = blk * HB;

  // ---- stage W as bf16 fragments (once) ----
  for (int idx = tid; idx < 2 * (KS_H + KS_X) * 64; idx += NTH) {
    int nt = idx / ((KS_H + KS_X) * 64);
    int rem = idx % ((KS_H + KS_X) * 64);
    int ks = rem >> 6, ll = rem & 63;
    int colq = nt * 16 + (ll & 15);          // block-local col 0..31
    int g = colq >> 3, j = colq & 7;         // gate, h-sub-index
    int r = g * HH + hb0 + j;                // global W row
    int k0 = (ll >> 4) * 8;
    float v[8];
    if (ks < KS_H) {
      const float* src = Whh + (size_t)r * HH + ks * 32 + k0;
      f32x4 u0 = *(const f32x4*)src;
      f32x4 u1 = *(const f32x4*)(src + 4);
      v[0] = u0.x; v[1] = u0.y; v[2] = u0.z; v[3] = u0.w;
      v[4] = u1.x; v[5] = u1.y; v[6] = u1.z; v[7] = u1.w;
    } else {
      int d0 = (ks - KS_H) * 32 + k0;
#pragma unroll
      for (int e = 0; e < 8; ++e)
        v[e] = (d0 + e < DD) ? Wih[(size_t)r * DD + d0 + e] : 0.f;
    }
    short8 pk;
#pragma unroll
    for (int e = 0; e < 8; ++e) pk[e] = (short)tobf(v[e]);
    Wlds[nt][ks][ll] = pk;
  }

  // ---- MFMA roles: wave = M-tile (16 batch rows); computes BOTH N-tiles ----
  const int row = w * 16 + (l & 15);   // batch row this lane's A-frag covers
  const int lk16 = (l >> 4);           // k-subchunk 0..3 (8 bf16 each)

  // ---- pointwise roles: lane = batch, wave w -> h-sub j0=2w, j1=2w+1 ----
  const int b = l, j0 = 2 * w, j1 = 2 * w + 1;
  const float gam0 = gammap[hb0 + j0], gam1 = gammap[hb0 + j1];
  const float bet0 = betap[hb0 + j0], bet1 = betap[hb0 + j1];
  const float msk0 = maskp[(size_t)b * HH + hb0 + j0];
  const float msk1 = maskp[(size_t)b * HH + hb0 + j1];
  const float biI0 = bih[0 * HH + hb0 + j0] + bhh[0 * HH + hb0 + j0];
  const float biF0 = bih[1 * HH + hb0 + j0] + bhh[1 * HH + hb0 + j0];
  const float biG0 = bih[2 * HH + hb0 + j0] + bhh[2 * HH + hb0 + j0];
  const float biO0 = bih[3 * HH + hb0 + j0] + bhh[3 * HH + hb0 + j0];
  const float biI1 = bih[0 * HH + hb0 + j1] + bhh[0 * HH + hb0 + j1];
  const float biF1 = bih[1 * HH + hb0 + j1] + bhh[1 * HH + hb0 + j1];
  const float biG1 = bih[2 * HH + hb0 + j1] + bhh[2 * HH + hb0 + j1];
  const float biO1 = bih[3 * HH + hb0 + j1] + bhh[3 * HH + hb0 + j1];
  const float fw0 = fcw[hb0 + j0], fw1 = fcw[hb0 + j1];
  float creg0 = 0.f, creg1 = 0.f;
  float pool0 = -3.4e38f, pool1 = -3.4e38f;
  __syncthreads();

  for (int s = 0; s < TT; ++s) {
    // h images in BLOCK-MAJOR layout: img[seg=128][b=64][8 cols] bf16.
    const unsigned short* hc = hbuf + (size_t)(s & 1) * (BB * HH);
    unsigned short* hnx = hbuf + (size_t)((s + 1) & 1) * (BB * HH);

    // ---- x part first (independent of h_s): 10 cached loads + 20 MFMAs ----
    const unsigned short* px = xbf + ((size_t)s * BB + row) * XPAD + lk16 * 8;
    short8 xa[KS_X];
#pragma unroll
    for (int i = 0; i < KS_X; ++i) ldA_nc(px + i * 32, xa[i]);
    WAITV(0);
    f32x4 acc0 = {0.f, 0.f, 0.f, 0.f}, acc1 = {0.f, 0.f, 0.f, 0.f};
#pragma unroll
    for (int i = 0; i < KS_X; ++i) {
      acc0 = mfma16(xa[i], Wlds[0][KS_H + i][l], acc0);
      acc1 = mfma16(xa[i], Wlds[1][KS_H + i][l], acc1);
    }

    // ---- wait for h_s publication ----
    poll_ge(slots, tid, (unsigned)s);

    // ---- h part: A-frag addr = hc + (ks*4 + lk16)*512 + row*8 ----
    const unsigned short* ph = hc + (size_t)lk16 * 512 + row * 8;
    short8 ha[KS_H];
#pragma unroll
    for (int i = 0; i < 8; ++i) ldA_sc(ph + i * 2048, ha[i]);        // c0
#pragma unroll
    for (int i = 8; i < 16; ++i) ldA_sc(ph + i * 2048, ha[i]);       // c1
    WAITV(8);  // c0 done
#pragma unroll
    for (int i = 16; i < 24; ++i) ldA_sc(ph + i * 2048, ha[i]);      // c2
#pragma unroll
    for (int i = 0; i < 8; ++i) {
      acc0 = mfma16(ha[i], Wlds[0][i][l], acc0);
      acc1 = mfma16(ha[i], Wlds[1][i][l], acc1);
    }
    WAITV(8);  // c1 done
#pragma unroll
    for (int i = 24; i < 32; ++i) ldA_sc(ph + i * 2048, ha[i]);      // c3
#pragma unroll
    for (int i = 8; i < 16; ++i) {
      acc0 = mfma16(ha[i], Wlds[0][i][l], acc0);
      acc1 = mfma16(ha[i], Wlds[1][i][l], acc1);
    }
    WAITV(8);  // c2 done
#pragma unroll
    for (int i = 16; i < 24; ++i) {
      acc0 = mfma16(ha[i], Wlds[0][i][l], acc0);
      acc1 = mfma16(ha[i], Wlds[1][i][l], acc1);
    }
    WAITV(0);  // c3 done
#pragma unroll
    for (int i = 24; i < 32; ++i) {
      acc0 = mfma16(ha[i], Wlds[0][i][l], acc0);
      acc1 = mfma16(ha[i], Wlds[1][i][l], acc1);
    }

    // ---- C exchange via LDS (C: col=lane&15, row=(lane>>4)*4+r) ----
    {
      int crow = w * 16 + (l >> 4) * 4;
      int cc0 = (l & 15), cc1 = 16 + (l & 15);
#pragma unroll
      for (int r = 0; r < 4; ++r) {
        Cs[crow + r][cc0] = acc0[r];
        Cs[crow + r][cc1] = acc1[r];
      }
    }
    __syncthreads();

    // ---- pointwise + BN + pool + coalesced publish ----
    float gI0 = Cs[b][j0] + biI0, gF0 = Cs[b][8 + j0] + biF0;
    float gG0 = Cs[b][16 + j0] + biG0, gO0 = Cs[b][24 + j0] + biO0;
    float gI1 = Cs[b][j1] + biI1, gF1 = Cs[b][8 + j1] + biF1;
    float gG1 = Cs[b][16 + j1] + biG1, gO1 = Cs[b][24 + j1] + biO1;
    float c20 = sigmoid_f(gF0) * creg0 + sigmoid_f(gI0) * tanh_f(gG0);
    float h20 = sigmoid_f(gO0) * tanh_f(c20);
    float c21 = sigmoid_f(gF1) * creg1 + sigmoid_f(gI1) * tanh_f(gG1);
    float h21 = sigmoid_f(gO1) * tanh_f(c21);
    creg0 = c20;
    creg1 = c21;
    float s10 = h20, s20 = h20 * h20, s11 = h21, s21 = h21 * h21;
#pragma unroll
    for (int off = 32; off; off >>= 1) {
      s10 += __shfl_xor(s10, off, 64);
      s20 += __shfl_xor(s20, off, 64);
      s11 += __shfl_xor(s11, off, 64);
      s21 += __shfl_xor(s21, off, 64);
    }
    float mu0 = s10 * (1.f / 64.f), var0 = fmaf(-mu0, mu0, s20 * (1.f / 64.f));
    float mu1 = s11 * (1.f / 64.f), var1 = fmaf(-mu1, mu1, s21 * (1.f / 64.f));
    float hn0 = gam0 * (h20 - mu0) * rsqrtf(var0 + BN_EPS) + bet0;
    float hn1 = gam1 * (h21 - mu1) * rsqrtf(var1 + BN_EPS) + bet1;
    pool0 = fmaxf(pool0, hn0 * msk0);
    pool1 = fmaxf(pool1, hn1 * msk1);
    // publish into our 1KB segment: dword at blk*1024B + b*16B + w*4B
    unsigned pk = (unsigned)tobf(h20) | ((unsigned)tobf(h21) << 16);
    st_sc32((unsigned*)(hnx + (size_t)blk * 512 + b * 8) + w, pk);  // wave-drained
    __syncthreads();
    if (tid == 0) st_sc32(&slots[blk], (unsigned)(s + 1));
  }

  // ---- per-block FC partial ----
  red_s[w][b] = pool0 * fw0 + pool1 * fw1;
  __syncthreads();
  if (tid < BB) {
    float part = red_s[0][tid] + red_s[1][tid] + red_s[2][tid] + red_s[3][tid];
    st_sc32(&partial[(size_t)tid * NBLK + blk], __float_as_uint(part));
  }
  __syncthreads();
  if (tid == 0) st_sc32(&slots[blk], (unsigned)(TT + 1));
  if (blk != 0) return;

  // ---- block 0: final reduction + loss ----
  poll_ge(slots, tid, (unsigned)(TT + 1));
  {
    int fb = tid & 63, q = tid >> 6;
    const float* pp = partial + ((size_t)fb * NBLK + q * 32);
    f32x4 v0, v1, v2, v3, v4, v5, v6, v7;
    ld4_sc(pp + 0, v0);  ld4_sc(pp + 4, v1);  ld4_sc(pp + 8, v2);  ld4_sc(pp + 12, v3);
    ld4_sc(pp + 16, v4); ld4_sc(pp + 20, v5); ld4_sc(pp + 24, v6); ld4_sc(pp + 28, v7);
    WAITV(0);
    float sum = v0.x + v0.y + v0.z + v0.w + v1.x + v1.y + v1.z + v1.w +
                v2.x + v2.y + v2.z + v2.w + v3.x + v3.y + v3.z + v3.w +
                v4.x + v4.y + v4.z + v4.w + v5.x + v5.y + v5.z + v5.w +
                v6.x + v6.y + v6.z + v6.w + v7.x + v7.y + v7.z + v7.w;
    red_s[q][fb] = sum;
  }
  __syncthreads();
  if (tid < BB) {
    float z = red_s[0][tid] + red_s[1][tid] + red_s[2][tid] + red_s[3][tid] + fcb[0];
    outp[1 + tid] = z;
    float sp = fmaxf(z, 0.f) + log1pf(__expf(-fabsf(z)));
    float lt = sp - z * tlbl[tid];
#pragma unroll
    for (int off = 32; off; off >>= 1) lt += __shfl_xor(lt, off, 64);
    if (tid == 0) outp[0] = lt * (1.f / 64.f);
  }
}

extern "C" void kernel_launch(void* const* d_in, const int* in_sizes, int n_in,
                              void* d_out, int out_size, void* d_ws, size_t ws_size,
                              hipStream_t stream) {
  const float* x = (const float*)d_in[0];
  const float* tlbl = (const float*)d_in[1];
  const float* maskp = (const float*)d_in[2];
  const float* Wih = (const float*)d_in[3];
  const float* Whh = (const float*)d_in[4];
  const float* bih = (const float*)d_in[5];
  const float* bhh = (const float*)d_in[6];
  const float* gammap = (const float*)d_in[7];
  const float* betap = (const float*)d_in[8];
  const float* fcw = (const float*)d_in[9];
  const float* fcb = (const float*)d_in[10];
  float* outp = (float*)d_out;

  // ws: slots(512B)+pad @0 | hbuf 2x128KB @4KB | partial 32KB | xbf 20.5MB
  unsigned* slots = (unsigned*)d_ws;
  unsigned short* hbuf = (unsigned short*)((char*)d_ws + 4096);
  float* partial = (float*)((char*)d_ws + 4096 + 2 * BB * HH * 2);
  unsigned short* xbf =
      (unsigned short*)((char*)d_ws + 4096 + 2 * BB * HH * 2 + BB * NBLK * 4);

  // zero slots + h image 0 (contiguous from ws base: 4096 + 128KB)
  int ndw = (4096 + BB * HH * 2) / 4;
  hipLaunchKernelGGL(init_k, dim3(64), dim3(NTH), 0, stream, (unsigned*)d_ws, ndw);
  hipLaunchKernelGGL(xcvt_k, dim3(2048), dim3(NTH), 0, stream, x, xbf);
  hipLaunchKernelGGL(lstm_mfma, dim3(NBLK), dim3(NTH), 0, stream,
                     Wih, Whh, bih, bhh, gammap, betap, maskp, tlbl, fcw, fcb,
                     xbf, hbuf, partial, slots, outp);
}